// Round 3
// baseline (282.096 us; speedup 1.0000x reference)
//
#include <hip/hip_runtime.h>
#include <math.h>

#define QN 21760
#define MTOT 43520   // = 340 * 128
#define SZBQC 11141120  // MTOT*256

typedef __attribute__((ext_vector_type(8))) short bf16x8;
typedef __attribute__((ext_vector_type(4))) float f32x4;

__device__ inline ushort f2bf(float f) {
  union { float f; uint u; } v; v.f = f;
  return (ushort)((v.u + 0x7FFFu + ((v.u >> 16) & 1u)) >> 16);
}
__device__ inline uint pk2(float lo, float hi) { return (uint)f2bf(lo) | ((uint)f2bf(hi) << 16); }

__device__ inline void g2l(const ushort* g, ushort* l) {
  __builtin_amdgcn_global_load_lds(
      (const __attribute__((address_space(1))) void*)g,
      (__attribute__((address_space(3))) void*)l, 16, 0, 0);
}

// ---------------- weight prep ----------------
__global__ __launch_bounds__(256) void prep_weights(
    const float* __restrict__ Wv, const float* __restrict__ Wout,
    const float* __restrict__ Woff, const float* __restrict__ Wattn,
    const float* __restrict__ boff, const float* __restrict__ battn,
    ushort* __restrict__ wv_t, ushort* __restrict__ wout_t,
    ushort* __restrict__ wol_t, float* __restrict__ biasf) {
  int bidx = blockIdx.x, t = threadIdx.x;
  if (bidx < 256) {
    int idx = bidx * 256 + t; int n = idx >> 8, k = idx & 255;
    wv_t[idx] = f2bf(Wv[(size_t)k * 256 + n]);
  } else if (bidx < 512) {
    int idx = (bidx - 256) * 256 + t; int n = idx >> 8, k = idx & 255;
    wout_t[idx] = f2bf(Wout[(size_t)k * 256 + n]);
  } else {
    int idx = (bidx - 512) * 256 + t; int n = idx >> 8, k = idx & 255;
    float v = (n < 256) ? Woff[(size_t)k * 256 + n] : Wattn[(size_t)k * 128 + (n - 256)];
    wol_t[idx] = f2bf(v);
    if (idx < 384) biasf[idx] = (idx < 256) ? boff[idx] : battn[idx - 256];
  }
}

// ---- XOR-swizzled LDS tile: 128 rows x 32 ushort; 16B chunk c of row r
// lives at physical chunk c ^ ((r>>1)&3). Frag reads are conflict-free. ----

// ---------------- fused input GEMM (val + offlog) ----------------
__global__ __launch_bounds__(256) void gemm_in(
    const float* __restrict__ value, const float* __restrict__ query,
    const ushort* __restrict__ Wv, const ushort* __restrict__ Wol,
    const float* __restrict__ bv, const float* __restrict__ bol,
    ushort* __restrict__ val_out, float* __restrict__ offlog) {
  __shared__ ushort As[2][4096];
  __shared__ ushort Bs[2][4096];
  const int t = threadIdx.x, wave = t >> 6, lane = t & 63;
  const int bx = blockIdx.y, bm = blockIdx.x * 128;
  const bool isVal = bx < 2;
  const float* A   = isVal ? value : query;
  const ushort* Bt = isVal ? (Wv + (size_t)bx * 128 * 256)
                           : (Wol + (size_t)(bx - 2) * 128 * 256);
  const int wm = (wave >> 1) * 64, wn = (wave & 1) * 64;
  const int l15 = lane & 15, l4 = lane >> 4;
  const int pc = l4 ^ ((l15 >> 1) & 3);              // frag-read physical chunk

  const int srow = lane >> 2;
  const int sch  = (lane & 3) ^ ((lane >> 3) & 3);
  const ushort* Bg = Bt + (size_t)(32 * wave + srow) * 256 + sch * 8;
  ushort* lb[2] = { &Bs[0][(32 * wave) * 32], &Bs[1][(32 * wave) * 32] };

  f32x4 acc[4][4];
#pragma unroll
  for (int i = 0; i < 4; ++i)
#pragma unroll
    for (int j = 0; j < 4; ++j) acc[i][j] = (f32x4){0.f, 0.f, 0.f, 0.f};

  int arow[4], apart[4];
#pragma unroll
  for (int i = 0; i < 4; ++i) {
    int c = t + i * 256; arow[i] = c >> 3; apart[i] = c & 7;
  }

  {
    float4 pa[4];
#pragma unroll
    for (int i = 0; i < 4; ++i)
      pa[i] = *(const float4*)&A[(size_t)(bm + arow[i]) * 256 + apart[i] * 4];
    g2l(Bg, lb[0]); g2l(Bg + 16 * 256, lb[0] + 16 * 32);
#pragma unroll
    for (int i = 0; i < 4; ++i) {
      int pc16 = (apart[i] >> 1) ^ ((arow[i] >> 1) & 3);
      ushort4 hv = { f2bf(pa[i].x), f2bf(pa[i].y), f2bf(pa[i].z), f2bf(pa[i].w) };
      *(ushort4*)&As[0][arow[i] * 32 + pc16 * 8 + (apart[i] & 1) * 4] = hv;
    }
  }

  for (int k = 0; k < 8; ++k) {
    __syncthreads();
    const int cur = k & 1, nxt = cur ^ 1;
    float4 pa[4];
    if (k < 7) {
      int k1 = (k + 1) * 32;
#pragma unroll
      for (int i = 0; i < 4; ++i)
        pa[i] = *(const float4*)&A[(size_t)(bm + arow[i]) * 256 + k1 + apart[i] * 4];
      g2l(Bg + k1, lb[nxt]); g2l(Bg + 16 * 256 + k1, lb[nxt] + 16 * 32);
    }
    bf16x8 af[4], bfr[4];
#pragma unroll
    for (int mi = 0; mi < 4; ++mi)
      af[mi] = *(const bf16x8*)&As[cur][(wm + mi * 16 + l15) * 32 + pc * 8];
#pragma unroll
    for (int ni = 0; ni < 4; ++ni)
      bfr[ni] = *(const bf16x8*)&Bs[cur][(wn + ni * 16 + l15) * 32 + pc * 8];
#pragma unroll
    for (int mi = 0; mi < 4; ++mi)
#pragma unroll
      for (int ni = 0; ni < 4; ++ni)
        acc[mi][ni] = __builtin_amdgcn_mfma_f32_16x16x32_bf16(af[mi], bfr[ni], acc[mi][ni], 0, 0, 0);
    if (k < 7) {
#pragma unroll
      for (int i = 0; i < 4; ++i) {
        int pc16 = (apart[i] >> 1) ^ ((arow[i] >> 1) & 3);
        ushort4 hv = { f2bf(pa[i].x), f2bf(pa[i].y), f2bf(pa[i].z), f2bf(pa[i].w) };
        *(ushort4*)&As[nxt][arow[i] * 32 + pc16 * 8 + (apart[i] & 1) * 4] = hv;
      }
    }
  }

  if (isVal) {
    _Float16* vo = (_Float16*)val_out;
#pragma unroll
    for (int mi = 0; mi < 4; ++mi)
#pragma unroll
      for (int ni = 0; ni < 4; ++ni) {
        int col = bx * 128 + wn + ni * 16 + l15;
        float bb = bv[col];
        int hh = col >> 5, c = col & 31;
#pragma unroll
        for (int r = 0; r < 4; ++r) {
          int row = bm + wm + mi * 16 + l4 * 4 + r;
          int b = (row >= QN) ? 1 : 0;
          int vpos = row - b * QN;
          vo[((size_t)(b * 8 + hh) * QN + vpos) * 32 + c] = (_Float16)(acc[mi][ni][r] + bb);
        }
      }
  } else {
#pragma unroll
    for (int mi = 0; mi < 4; ++mi)
#pragma unroll
      for (int ni = 0; ni < 4; ++ni) {
        int col = (bx - 2) * 128 + wn + ni * 16 + l15;
        float bb = bol[col];
#pragma unroll
        for (int r = 0; r < 4; ++r) {
          int row = bm + wm + mi * 16 + l4 * 4 + r;
          offlog[(size_t)row * 384 + col] = acc[mi][ni][r] + bb;
        }
      }
  }
}

// ---------------- output GEMM (A bf16), dbuf, all-g2l, swizzled ----------------
__global__ __launch_bounds__(256) void gemm_out(
    const ushort* __restrict__ A, const ushort* __restrict__ Bt,
    const float* __restrict__ bias, float* __restrict__ C) {
  __shared__ ushort As[2][4096];
  __shared__ ushort Bs[2][4096];
  const int t = threadIdx.x, wave = t >> 6, lane = t & 63;
  const int bm = blockIdx.x * 128, bn = blockIdx.y * 128;
  const int wm = (wave >> 1) * 64, wn = (wave & 1) * 64;
  const int l15 = lane & 15, l4 = lane >> 4;
  const int pc = l4 ^ ((l15 >> 1) & 3);

  const int srow = lane >> 2;
  const int sch  = (lane & 3) ^ ((lane >> 3) & 3);
  const ushort* Ag = A + (size_t)(bm + 32 * wave + srow) * 256 + sch * 8;
  const ushort* Bg = Bt + (size_t)(bn + 32 * wave + srow) * 256 + sch * 8;
  ushort* la[2] = { &As[0][(32 * wave) * 32], &As[1][(32 * wave) * 32] };
  ushort* lb[2] = { &Bs[0][(32 * wave) * 32], &Bs[1][(32 * wave) * 32] };

  f32x4 acc[4][4];
#pragma unroll
  for (int i = 0; i < 4; ++i)
#pragma unroll
    for (int j = 0; j < 4; ++j) acc[i][j] = (f32x4){0.f, 0.f, 0.f, 0.f};

  g2l(Ag, la[0]); g2l(Ag + 16 * 256, la[0] + 16 * 32);
  g2l(Bg, lb[0]); g2l(Bg + 16 * 256, lb[0] + 16 * 32);

  for (int k = 0; k < 8; ++k) {
    __syncthreads();
    const int cur = k & 1, nxt = cur ^ 1;
    if (k < 7) {
      int k1 = (k + 1) * 32;
      g2l(Ag + k1, la[nxt]); g2l(Ag + 16 * 256 + k1, la[nxt] + 16 * 32);
      g2l(Bg + k1, lb[nxt]); g2l(Bg + 16 * 256 + k1, lb[nxt] + 16 * 32);
    }
    bf16x8 af[4], bfr[4];
#pragma unroll
    for (int mi = 0; mi < 4; ++mi)
      af[mi] = *(const bf16x8*)&As[cur][(wm + mi * 16 + l15) * 32 + pc * 8];
#pragma unroll
    for (int ni = 0; ni < 4; ++ni)
      bfr[ni] = *(const bf16x8*)&Bs[cur][(wn + ni * 16 + l15) * 32 + pc * 8];
#pragma unroll
    for (int mi = 0; mi < 4; ++mi)
#pragma unroll
      for (int ni = 0; ni < 4; ++ni)
        acc[mi][ni] = __builtin_amdgcn_mfma_f32_16x16x32_bf16(af[mi], bfr[ni], acc[mi][ni], 0, 0, 0);
  }

#pragma unroll
  for (int mi = 0; mi < 4; ++mi)
#pragma unroll
    for (int ni = 0; ni < 4; ++ni) {
      int col = bn + wn + ni * 16 + l15;
      float bb = bias[col];
#pragma unroll
      for (int r = 0; r < 4; ++r) {
        int row = bm + wm + mi * 16 + l4 * 4 + r;
        C[(size_t)row * 256 + col] = acc[mi][ni][r] + bb;
      }
    }
}

// ---------------- deformable sampling ----------------
// v3: 8 sub-lanes per (b,q,h). Lanes 0-3 = x-side 0 (4 channel-chunks),
// lanes 4-7 = x-side 1. Each point needs only TWO wave-loads (row y0 and
// row y1), each covering the contiguous 128B [x0|x0+1] pixel pair across
// 8 lanes -> 8 disjoint segments per wave-instruction instead of 16.
// Loads come from xbase=clamp(x0,0,W-2); each lane's x-weight is selected
// by index-match against the reference's clamped corner indices, which
// reproduces clamp+mask semantics exactly (incl. double-clamp edges) and
// keeps all reads in-plane (finite). Final __shfl_xor(4) merges x-sides.
__device__ inline void fmah(float* a, uint4 u, float wv) {
  union { uint4 u; _Float16 h[8]; } c; c.u = u;
#pragma unroll
  for (int i = 0; i < 8; ++i) a[i] = fmaf((float)c.h[i], wv, a[i]);
}

__global__ __launch_bounds__(256) void msda_sample(
    const ushort* __restrict__ val, const float* __restrict__ offlog,
    const float* __restrict__ ref, ushort* __restrict__ interm) {
  const int lsz[4]    = {128, 64, 32, 16};
  const int lstart[4] = {0, 16384, 20480, 21504};

  int h     = blockIdx.x & 7;
  int z     = blockIdx.x >> 3;              // 0..1359
  int sub   = threadIdx.x & 7;
  int chq   = sub & 3;
  int xside = sub >> 2;                     // 0 or 1
  int bq    = z * 32 + (threadIdx.x >> 3);  // 1360*32 = 43520
  int b     = (bq >= QN) ? 1 : 0;
  const uint plane = (uint)(b * 8 + h) * (uint)QN * 32u;  // ushort elements
  const uint choff = (uint)chq * 8u + (uint)xside * 32u;

  // attention logits -> softmax, pre-scaled by 1/sum
  const float* lgp = offlog + (size_t)bq * 384 + 256 + h * 16;
  float w[16];
  {
    float4 a0 = *(const float4*)(lgp);
    float4 a1 = *(const float4*)(lgp + 4);
    float4 a2 = *(const float4*)(lgp + 8);
    float4 a3 = *(const float4*)(lgp + 12);
    w[0]=a0.x; w[1]=a0.y; w[2]=a0.z; w[3]=a0.w;
    w[4]=a1.x; w[5]=a1.y; w[6]=a1.z; w[7]=a1.w;
    w[8]=a2.x; w[9]=a2.y; w[10]=a2.z; w[11]=a2.w;
    w[12]=a3.x; w[13]=a3.y; w[14]=a3.z; w[15]=a3.w;
  }
  float m = -1e30f;
#pragma unroll
  for (int s = 0; s < 16; ++s) m = fmaxf(m, w[s]);
  float sum = 0.f;
#pragma unroll
  for (int s = 0; s < 16; ++s) { w[s] = __expf(w[s] - m); sum += w[s]; }
  float inv = __builtin_amdgcn_rcpf(sum);
#pragma unroll
  for (int s = 0; s < 16; ++s) w[s] *= inv;

  const float* offp = offlog + (size_t)bq * 384 + h * 32;
  const float* refp = ref + (size_t)bq * 8;

  float acc[8];
#pragma unroll
  for (int i = 0; i < 8; ++i) acc[i] = 0.f;

#pragma unroll
  for (int l = 0; l < 4; ++l) {
    const int  W = lsz[l];
    const uint lvlbase = plane + (uint)lstart[l] * 32u + choff;
    float4 o0 = *(const float4*)(offp + l * 8);
    float4 o1 = *(const float4*)(offp + l * 8 + 4);
    float ox[4] = { o0.x, o0.z, o1.x, o1.z };
    float oy[4] = { o0.y, o0.w, o1.y, o1.w };
    const float fW = (float)W;
    const float xb = refp[l * 2 + 0] * fW - 0.5f;
    const float yb = refp[l * 2 + 1] * fW - 0.5f;

#pragma unroll
    for (int p = 0; p < 4; ++p) {
      float x = xb + ox[p];
      float y = yb + oy[p];
      float x0f = floorf(x), y0f = floorf(y);
      float fx = x - x0f,    fy = y - y0f;
      int   x0 = (int)x0f,   y0 = (int)y0f;
      float a = w[l * 4 + p];
      // masked corner weights (reference semantics)
      float wx0 = ((uint)x0       < (uint)W) ? (1.f - fx) : 0.f;
      float wx1 = ((uint)(x0 + 1) < (uint)W) ? fx         : 0.f;
      float wy0a = (((uint)y0       < (uint)W) ? (1.f - fy) : 0.f) * a;
      float wy1a = (((uint)(y0 + 1) < (uint)W) ? fy         : 0.f) * a;
      // clamped corner indices (reference semantics)
      int xc0 = min(max(x0, 0), W - 1);
      int xc1 = min(max(x0 + 1, 0), W - 1);
      int yc0 = min(max(y0, 0), W - 1);
      int yc1 = min(max(y0 + 1, 0), W - 1);
      // aligned pair base; this lane reads pixel px = xbase + xside
      int xbase = max(min(x0, W - 2), 0);
      int px    = xbase + xside;
      // lane's x-weight: sum of reference corner weights landing on px
      float wlx = ((px == xc0) ? wx0 : 0.f) + ((px == xc1) ? wx1 : 0.f);
      uint ro0 = lvlbase + (uint)((yc0 * W + xbase) * 32);
      uint ro1 = lvlbase + (uint)((yc1 * W + xbase) * 32);
      uint4 u0 = *(const uint4*)(val + ro0);
      uint4 u1 = *(const uint4*)(val + ro1);
      fmah(acc, u0, wlx * wy0a);
      fmah(acc, u1, wlx * wy1a);
    }
  }

  // merge x-sides (lanes s and s^4 hold the two halves of the same chq)
#pragma unroll
  for (int i = 0; i < 8; ++i) acc[i] += __shfl_xor(acc[i], 4, 64);

  // each lane stores 8B: xside 0 -> channels [chq*8, +4), xside 1 -> +4..8
  uint2 o;
  if (xside == 0) { o.x = pk2(acc[0], acc[1]); o.y = pk2(acc[2], acc[3]); }
  else            { o.x = pk2(acc[4], acc[5]); o.y = pk2(acc[6], acc[7]); }
  *(uint2*)(interm + (size_t)bq * 256 + h * 32 + chq * 8 + xside * 4) = o;
}

extern "C" void kernel_launch(void* const* d_in, const int* in_sizes, int n_in,
                              void* d_out, int out_size, void* d_ws, size_t ws_size,
                              hipStream_t stream) {
  const float* query = (const float*)d_in[0];
  const float* value = (const float*)d_in[1];
  const float* ref   = (const float*)d_in[2];
  const float* W_off  = (const float*)d_in[4];
  const float* b_off  = (const float*)d_in[5];
  const float* W_attn = (const float*)d_in[6];
  const float* b_attn = (const float*)d_in[7];
  const float* W_v    = (const float*)d_in[8];
  const float* b_v    = (const float*)d_in[9];
  const float* W_out  = (const float*)d_in[10];
  const float* b_out  = (const float*)d_in[11];
  float* out = (float*)d_out;

  // ---- workspace (byte offsets, 256-aligned) ----
  char* wsb = (char*)d_ws;
  ushort* ws_wv     = (ushort*)(wsb + 0);          // 131072 B
  ushort* ws_wol    = (ushort*)(wsb + 131072);     // 196608 B
  ushort* ws_wout   = (ushort*)(wsb + 327680);     // 131072 B
  float*  ws_biasf  = (float*)(wsb + 458752);      // 4096 B
  ushort* ws_val    = (ushort*)(wsb + 462848);     // 22282240 B fp16 head-split
  ushort* ws_interm = (ushort*)(wsb + 22745088);   // 22282240 B bf16 (M,256)
  float*  ws_offlog = (float*)(wsb + 45027328);    // 66846720 B f32 (M,384)
  size_t need = (size_t)45027328 + 66846720;       // ~112 MB
  if (ws_size < need) return;

  dim3 blk(256);
  prep_weights<<<dim3(896), blk, 0, stream>>>(W_v, W_out, W_off, W_attn, b_off, b_attn,
                                              ws_wv, ws_wout, ws_wol, ws_biasf);
  gemm_in<<<dim3(340, 5), blk, 0, stream>>>(value, query, ws_wv, ws_wol, b_v, ws_biasf,
                                            ws_val, ws_offlog);
  msda_sample<<<dim3(10880), blk, 0, stream>>>(ws_val, ws_offlog, ref, ws_interm);
  gemm_out<<<dim3(340, 2), blk, 0, stream>>>(ws_interm, ws_wout, b_out, out);
}

// Round 6
// 277.294 us; speedup vs baseline: 1.0173x; 1.0173x over previous
//
#include <hip/hip_runtime.h>
#include <math.h>

#define QN 21760
#define MTOT 43520   // = 340 * 128
#define SZBQC 11141120  // MTOT*256

typedef __attribute__((ext_vector_type(8))) short bf16x8;
typedef __attribute__((ext_vector_type(4))) float f32x4;

__device__ inline ushort f2bf(float f) {
  union { float f; uint u; } v; v.f = f;
  return (ushort)((v.u + 0x7FFFu + ((v.u >> 16) & 1u)) >> 16);
}
__device__ inline uint pk2(float lo, float hi) { return (uint)f2bf(lo) | ((uint)f2bf(hi) << 16); }

__device__ inline void g2l(const ushort* g, ushort* l) {
  __builtin_amdgcn_global_load_lds(
      (const __attribute__((address_space(1))) void*)g,
      (__attribute__((address_space(3))) void*)l, 16, 0, 0);
}

// ---------------- weight prep ----------------
__global__ __launch_bounds__(256) void prep_weights(
    const float* __restrict__ Wv, const float* __restrict__ Wout,
    const float* __restrict__ Woff, const float* __restrict__ Wattn,
    const float* __restrict__ boff, const float* __restrict__ battn,
    ushort* __restrict__ wv_t, ushort* __restrict__ wout_t,
    ushort* __restrict__ wol_t, float* __restrict__ biasf) {
  int bidx = blockIdx.x, t = threadIdx.x;
  if (bidx < 256) {
    int idx = bidx * 256 + t; int n = idx >> 8, k = idx & 255;
    wv_t[idx] = f2bf(Wv[(size_t)k * 256 + n]);
  } else if (bidx < 512) {
    int idx = (bidx - 256) * 256 + t; int n = idx >> 8, k = idx & 255;
    wout_t[idx] = f2bf(Wout[(size_t)k * 256 + n]);
  } else {
    int idx = (bidx - 512) * 256 + t; int n = idx >> 8, k = idx & 255;
    float v = (n < 256) ? Woff[(size_t)k * 256 + n] : Wattn[(size_t)k * 128 + (n - 256)];
    wol_t[idx] = f2bf(v);
    if (idx < 384) biasf[idx] = (idx < 256) ? boff[idx] : battn[idx - 256];
  }
}

// ---- XOR-swizzled LDS tile: 128 rows x 32 ushort; 16B chunk c of row r
// lives at physical chunk c ^ ((r>>1)&3). Frag reads are conflict-free. ----

// ---------------- fused input GEMM (val + offlog) ----------------
// 1-D grid 1720, XCD-bijective decode: all 5 output panels of a given bm
// land on the SAME XCD with consecutive queue slots -> A-tile L2 reuse.
__global__ __launch_bounds__(256) void gemm_in(
    const float* __restrict__ value, const float* __restrict__ query,
    const ushort* __restrict__ Wv, const ushort* __restrict__ Wol,
    const float* __restrict__ bv, const float* __restrict__ bol,
    ushort* __restrict__ val_out, float* __restrict__ offlog) {
  __shared__ ushort As[2][4096];
  __shared__ ushort Bs[2][4096];
  const int bid = blockIdx.x;
  const int q5  = bid >> 3;
  const int bxv = (bid & 7) + 8 * (q5 / 5);       // bm index 0..343
  const int bx  = q5 % 5;                          // panel
  if (bxv >= 340) return;
  const int t = threadIdx.x, wave = t >> 6, lane = t & 63;
  const int bm = bxv * 128;
  const bool isVal = bx < 2;
  const float* A   = isVal ? value : query;
  const ushort* Bt = isVal ? (Wv + (size_t)bx * 128 * 256)
                           : (Wol + (size_t)(bx - 2) * 128 * 256);
  const int wm = (wave >> 1) * 64, wn = (wave & 1) * 64;
  const int l15 = lane & 15, l4 = lane >> 4;
  const int pc = l4 ^ ((l15 >> 1) & 3);              // frag-read physical chunk

  const int srow = lane >> 2;
  const int sch  = (lane & 3) ^ ((lane >> 3) & 3);
  const ushort* Bg = Bt + (size_t)(32 * wave + srow) * 256 + sch * 8;
  ushort* lb[2] = { &Bs[0][(32 * wave) * 32], &Bs[1][(32 * wave) * 32] };

  f32x4 acc[4][4];
#pragma unroll
  for (int i = 0; i < 4; ++i)
#pragma unroll
    for (int j = 0; j < 4; ++j) acc[i][j] = (f32x4){0.f, 0.f, 0.f, 0.f};

  int arow[4], apart[4];
#pragma unroll
  for (int i = 0; i < 4; ++i) {
    int c = t + i * 256; arow[i] = c >> 3; apart[i] = c & 7;
  }

  {
    float4 pa[4];
#pragma unroll
    for (int i = 0; i < 4; ++i)
      pa[i] = *(const float4*)&A[(size_t)(bm + arow[i]) * 256 + apart[i] * 4];
    g2l(Bg, lb[0]); g2l(Bg + 16 * 256, lb[0] + 16 * 32);
#pragma unroll
    for (int i = 0; i < 4; ++i) {
      int pc16 = (apart[i] >> 1) ^ ((arow[i] >> 1) & 3);
      ushort4 hv = { f2bf(pa[i].x), f2bf(pa[i].y), f2bf(pa[i].z), f2bf(pa[i].w) };
      *(ushort4*)&As[0][arow[i] * 32 + pc16 * 8 + (apart[i] & 1) * 4] = hv;
    }
  }

  for (int k = 0; k < 8; ++k) {
    __syncthreads();
    const int cur = k & 1, nxt = cur ^ 1;
    float4 pa[4];
    if (k < 7) {
      int k1 = (k + 1) * 32;
#pragma unroll
      for (int i = 0; i < 4; ++i)
        pa[i] = *(const float4*)&A[(size_t)(bm + arow[i]) * 256 + k1 + apart[i] * 4];
      g2l(Bg + k1, lb[nxt]); g2l(Bg + 16 * 256 + k1, lb[nxt] + 16 * 32);
    }
    bf16x8 af[4], bfr[4];
#pragma unroll
    for (int mi = 0; mi < 4; ++mi)
      af[mi] = *(const bf16x8*)&As[cur][(wm + mi * 16 + l15) * 32 + pc * 8];
#pragma unroll
    for (int ni = 0; ni < 4; ++ni)
      bfr[ni] = *(const bf16x8*)&Bs[cur][(wn + ni * 16 + l15) * 32 + pc * 8];
#pragma unroll
    for (int mi = 0; mi < 4; ++mi)
#pragma unroll
      for (int ni = 0; ni < 4; ++ni)
        acc[mi][ni] = __builtin_amdgcn_mfma_f32_16x16x32_bf16(af[mi], bfr[ni], acc[mi][ni], 0, 0, 0);
    if (k < 7) {
#pragma unroll
      for (int i = 0; i < 4; ++i) {
        int pc16 = (apart[i] >> 1) ^ ((arow[i] >> 1) & 3);
        ushort4 hv = { f2bf(pa[i].x), f2bf(pa[i].y), f2bf(pa[i].z), f2bf(pa[i].w) };
        *(ushort4*)&As[nxt][arow[i] * 32 + pc16 * 8 + (apart[i] & 1) * 4] = hv;
      }
    }
  }

  if (isVal) {
    _Float16* vo = (_Float16*)val_out;
#pragma unroll
    for (int mi = 0; mi < 4; ++mi)
#pragma unroll
      for (int ni = 0; ni < 4; ++ni) {
        int col = bx * 128 + wn + ni * 16 + l15;
        float bb = bv[col];
        int hh = col >> 5, c = col & 31;
#pragma unroll
        for (int r = 0; r < 4; ++r) {
          int row = bm + wm + mi * 16 + l4 * 4 + r;
          int b = (row >= QN) ? 1 : 0;
          int vpos = row - b * QN;
          vo[((size_t)(b * 8 + hh) * QN + vpos) * 32 + c] = (_Float16)(acc[mi][ni][r] + bb);
        }
      }
  } else {
#pragma unroll
    for (int mi = 0; mi < 4; ++mi)
#pragma unroll
      for (int ni = 0; ni < 4; ++ni) {
        int col = (bx - 2) * 128 + wn + ni * 16 + l15;
        float bb = bol[col];
#pragma unroll
        for (int r = 0; r < 4; ++r) {
          int row = bm + wm + mi * 16 + l4 * 4 + r;
          offlog[(size_t)row * 384 + col] = acc[mi][ni][r] + bb;
        }
      }
  }
}

// ---------------- output GEMM (A bf16), dbuf, all-g2l, swizzled ----------------
__global__ __launch_bounds__(256) void gemm_out(
    const ushort* __restrict__ A, const ushort* __restrict__ Bt,
    const float* __restrict__ bias, float* __restrict__ C) {
  __shared__ ushort As[2][4096];
  __shared__ ushort Bs[2][4096];
  const int bid = blockIdx.x;
  const int q2  = bid >> 3;
  const int bxv = (bid & 7) + 8 * (q2 >> 1);
  const int byv = q2 & 1;
  if (bxv >= 340) return;
  const int t = threadIdx.x, wave = t >> 6, lane = t & 63;
  const int bm = bxv * 128, bn = byv * 128;
  const int wm = (wave >> 1) * 64, wn = (wave & 1) * 64;
  const int l15 = lane & 15, l4 = lane >> 4;
  const int pc = l4 ^ ((l15 >> 1) & 3);

  const int srow = lane >> 2;
  const int sch  = (lane & 3) ^ ((lane >> 3) & 3);
  const ushort* Ag = A + (size_t)(bm + 32 * wave + srow) * 256 + sch * 8;
  const ushort* Bg = Bt + (size_t)(bn + 32 * wave + srow) * 256 + sch * 8;
  ushort* la[2] = { &As[0][(32 * wave) * 32], &As[1][(32 * wave) * 32] };
  ushort* lb[2] = { &Bs[0][(32 * wave) * 32], &Bs[1][(32 * wave) * 32] };

  f32x4 acc[4][4];
#pragma unroll
  for (int i = 0; i < 4; ++i)
#pragma unroll
    for (int j = 0; j < 4; ++j) acc[i][j] = (f32x4){0.f, 0.f, 0.f, 0.f};

  g2l(Ag, la[0]); g2l(Ag + 16 * 256, la[0] + 16 * 32);
  g2l(Bg, lb[0]); g2l(Bg + 16 * 256, lb[0] + 16 * 32);

  for (int k = 0; k < 8; ++k) {
    __syncthreads();
    const int cur = k & 1, nxt = cur ^ 1;
    if (k < 7) {
      int k1 = (k + 1) * 32;
      g2l(Ag + k1, la[nxt]); g2l(Ag + 16 * 256 + k1, la[nxt] + 16 * 32);
      g2l(Bg + k1, lb[nxt]); g2l(Bg + 16 * 256 + k1, lb[nxt] + 16 * 32);
    }
    bf16x8 af[4], bfr[4];
#pragma unroll
    for (int mi = 0; mi < 4; ++mi)
      af[mi] = *(const bf16x8*)&As[cur][(wm + mi * 16 + l15) * 32 + pc * 8];
#pragma unroll
    for (int ni = 0; ni < 4; ++ni)
      bfr[ni] = *(const bf16x8*)&Bs[cur][(wn + ni * 16 + l15) * 32 + pc * 8];
#pragma unroll
    for (int mi = 0; mi < 4; ++mi)
#pragma unroll
      for (int ni = 0; ni < 4; ++ni)
        acc[mi][ni] = __builtin_amdgcn_mfma_f32_16x16x32_bf16(af[mi], bfr[ni], acc[mi][ni], 0, 0, 0);
  }

#pragma unroll
  for (int mi = 0; mi < 4; ++mi)
#pragma unroll
    for (int ni = 0; ni < 4; ++ni) {
      int col = bn + wn + ni * 16 + l15;
      float bb = bias[col];
#pragma unroll
      for (int r = 0; r < 4; ++r) {
        int row = bm + wm + mi * 16 + l4 * 4 + r;
        C[(size_t)row * 256 + col] = acc[mi][ni][r] + bb;
      }
    }
}

// ---------------- deformable sampling ----------------
// v4: v2 skeleton (4 sub-lanes/(b,q,h), identical coalesced load pattern)
// + owner-lane de-replication: lane `sub` owns level `sub` — computes its
// 4 logits' exp (softmax reduced via 2 shfl_xor) and its level's 4 points'
// addresses+weights ONCE; consumers get them via __shfl broadcast (LDS
// pipe) instead of recomputing x4. Replicated per-point VALU ~640 -> ~190.
__device__ inline void fmah(float* a, uint4 u, float wv) {
  union { uint4 u; _Float16 h[8]; } c; c.u = u;
#pragma unroll
  for (int i = 0; i < 8; ++i) a[i] = fmaf((float)c.h[i], wv, a[i]);
}

__global__ __launch_bounds__(256) void msda_sample(
    const ushort* __restrict__ val, const float* __restrict__ offlog,
    const float* __restrict__ ref, ushort* __restrict__ interm) {
  int h   = blockIdx.x & 7;
  int z   = blockIdx.x >> 3;          // 0..679
  int sub = threadIdx.x & 3;
  int bq  = z * 64 + (threadIdx.x >> 2);   // 680*64 = 43520
  int b   = (bq >= QN) ? 1 : 0;
  const uint sub8 = (uint)(sub * 8);
  const ushort* vb = val + (size_t)((uint)(b * 8 + h) * (uint)QN) * 32u + sub8;

  // ---- softmax, distributed: lane owns level `sub`'s 4 logits ----
  const float* lgp = offlog + (size_t)bq * 384 + 256 + h * 16;
  float4 lg = *(const float4*)(lgp + sub * 4);
  float m = fmaxf(fmaxf(lg.x, lg.y), fmaxf(lg.z, lg.w));
  m = fmaxf(m, __shfl_xor(m, 1, 64));
  m = fmaxf(m, __shfl_xor(m, 2, 64));
  float e0 = __expf(lg.x - m), e1 = __expf(lg.y - m),
        e2 = __expf(lg.z - m), e3 = __expf(lg.w - m);
  float s = e0 + e1 + e2 + e3;
  s += __shfl_xor(s, 1, 64);
  s += __shfl_xor(s, 2, 64);
  float inv = __builtin_amdgcn_rcpf(s);
  float aw[4] = { e0 * inv, e1 * inv, e2 * inv, e3 * inv };

  // ---- owned level geometry (level = sub) ----
  const int  Wl  = 128 >> sub;                       // 128,64,32,16
  const uint t16 = 65536u >> (sub + sub);
  const int  lst = (int)((65536u - t16) / 3u);       // 0,16384,20480,21504
  const float fW = (float)Wl;
  const float* offp = offlog + (size_t)bq * 384 + h * 32;
  float4 o0 = *(const float4*)(offp + sub * 8);
  float4 o1 = *(const float4*)(offp + sub * 8 + 4);
  float2 rf = *(const float2*)(ref + (size_t)bq * 8 + sub * 2);
  const float xb = rf.x * fW - 0.5f;
  const float yb = rf.y * fW - 0.5f;
  float ox[4] = { o0.x, o0.z, o1.x, o1.z };
  float oy[4] = { o0.y, o0.w, o1.y, o1.w };

  uint  pA0[4], pA1[4], pDX[4];
  float pX0[4], pX1[4], pY0[4], pY1[4];
#pragma unroll
  for (int p = 0; p < 4; ++p) {
    float x = xb + ox[p], y = yb + oy[p];
    float x0f = floorf(x), y0f = floorf(y);
    float fx = x - x0f, fy = y - y0f;
    int x0 = (int)x0f, y0 = (int)y0f;
    float a = aw[p];
    // masked corner weights (reference semantics)
    pX0[p] = ((uint)x0       < (uint)Wl) ? (1.f - fx) : 0.f;
    pX1[p] = ((uint)(x0 + 1) < (uint)Wl) ? fx         : 0.f;
    pY0[p] = (((uint)y0       < (uint)Wl) ? (1.f - fy) : 0.f) * a;
    pY1[p] = (((uint)(y0 + 1) < (uint)Wl) ? fy         : 0.f) * a;
    // clamped corner indices (reference semantics)
    int xc0 = min(max(x0, 0), Wl - 1);
    int xc1 = min(max(x0 + 1, 0), Wl - 1);
    int yc0 = min(max(y0, 0), Wl - 1);
    int yc1 = min(max(y0 + 1, 0), Wl - 1);
    pA0[p] = (uint)((lst + yc0 * Wl + xc0) * 32);    // elem offset, row y0
    pA1[p] = (uint)((lst + yc1 * Wl + xc0) * 32);    // elem offset, row y1
    pDX[p] = (uint)((xc1 - xc0) * 32);               // 0 or 32
  }

  float acc[8];
#pragma unroll
  for (int i = 0; i < 8; ++i) acc[i] = 0.f;

  const int lanebase = (threadIdx.x & 63) & 60;      // lane & ~3
#pragma unroll
  for (int l = 0; l < 4; ++l) {
    const int src = lanebase | l;
#pragma unroll
    for (int p = 0; p < 4; ++p) {
      uint  A0  = (uint)__shfl((int)pA0[p], src, 64);
      uint  A1  = (uint)__shfl((int)pA1[p], src, 64);
      uint  DX  = (uint)__shfl((int)pDX[p], src, 64);
      float wx0 = __shfl(pX0[p], src, 64);
      float wx1 = __shfl(pX1[p], src, 64);
      float wy0 = __shfl(pY0[p], src, 64);
      float wy1 = __shfl(pY1[p], src, 64);
      uint4 u00 = *(const uint4*)(vb + A0);
      uint4 u01 = *(const uint4*)(vb + A0 + DX);
      uint4 u10 = *(const uint4*)(vb + A1);
      uint4 u11 = *(const uint4*)(vb + A1 + DX);
      fmah(acc, u00, wx0 * wy0);
      fmah(acc, u01, wx1 * wy0);
      fmah(acc, u10, wx0 * wy1);
      fmah(acc, u11, wx1 * wy1);
    }
  }

  uint4 o;
  o.x = pk2(acc[0], acc[1]); o.y = pk2(acc[2], acc[3]);
  o.z = pk2(acc[4], acc[5]); o.w = pk2(acc[6], acc[7]);
  *(uint4*)(interm + (size_t)bq * 256 + h * 32 + sub * 8) = o;
}

extern "C" void kernel_launch(void* const* d_in, const int* in_sizes, int n_in,
                              void* d_out, int out_size, void* d_ws, size_t ws_size,
                              hipStream_t stream) {
  const float* query = (const float*)d_in[0];
  const float* value = (const float*)d_in[1];
  const float* ref   = (const float*)d_in[2];
  const float* W_off  = (const float*)d_in[4];
  const float* b_off  = (const float*)d_in[5];
  const float* W_attn = (const float*)d_in[6];
  const float* b_attn = (const float*)d_in[7];
  const float* W_v    = (const float*)d_in[8];
  const float* b_v    = (const float*)d_in[9];
  const float* W_out  = (const float*)d_in[10];
  const float* b_out  = (const float*)d_in[11];
  float* out = (float*)d_out;

  // ---- workspace (byte offsets, 256-aligned) ----
  char* wsb = (char*)d_ws;
  ushort* ws_wv     = (ushort*)(wsb + 0);          // 131072 B
  ushort* ws_wol    = (ushort*)(wsb + 131072);     // 196608 B
  ushort* ws_wout   = (ushort*)(wsb + 327680);     // 131072 B
  float*  ws_biasf  = (float*)(wsb + 458752);      // 4096 B
  ushort* ws_val    = (ushort*)(wsb + 462848);     // 22282240 B fp16 head-split
  ushort* ws_interm = (ushort*)(wsb + 22745088);   // 22282240 B bf16 (M,256)
  float*  ws_offlog = (float*)(wsb + 45027328);    // 66846720 B f32 (M,384)
  size_t need = (size_t)45027328 + 66846720;       // ~112 MB
  if (ws_size < need) return;

  dim3 blk(256);
  prep_weights<<<dim3(896), blk, 0, stream>>>(W_v, W_out, W_off, W_attn, b_off, b_attn,
                                              ws_wv, ws_wout, ws_wol, ws_biasf);
  gemm_in<<<dim3(1720), blk, 0, stream>>>(value, query, ws_wv, ws_wol, b_v, ws_biasf,
                                          ws_val, ws_offlog);
  msda_sample<<<dim3(5440), blk, 0, stream>>>(ws_val, ws_offlog, ref, ws_interm);
  gemm_out<<<dim3(688), blk, 0, stream>>>(ws_interm, ws_wout, b_out, out);
}